// Round 8
// baseline (385.693 us; speedup 1.0000x reference)
//
#include <hip/hip_runtime.h>
#include <hip/hip_bf16.h>
#include <math.h>

#define T_LEN 4096
#define BATCH 16

// ---------------------------------------------------------------------------
// k_gcn: adapter + node projections + A_HAT propagation + relu + node-mean.
// t-tile 32 (LDS 31.4 KB -> 5 blocks/CU), thread = 4d x 2t (~105 VGPR).
// Bone weights in registers; palm weights in LDS; one lane-varying b64 x-read
// per 8 FMAs.  Output hp [B][64][T] channel-major.
// ---------------------------------------------------------------------------
__global__ __launch_bounds__(256) void k_gcn(
    const float* __restrict__ x,      // [B][T][218]
    const float* __restrict__ gcn_w,  // [18][64]
    float* __restrict__ hp)           // [B][64][T]
{
    __shared__ float xt[218 * 36];    // [c][32 t], stride 36
    __shared__ float wg[18 * 64];     // palm weights

    const int b   = blockIdx.y;
    const int t0  = blockIdx.x * 32;
    const int tid = threadIdx.x;

    const float* xb = x + ((long)b * T_LEN + t0) * 218;
    #pragma unroll 1
    for (int i = tid; i < 32 * 218; i += 256) {
        const int t = i / 218;
        const int c = i - 218 * t;
        xt[c * 36 + t] = xb[i];
    }
    for (int i = tid; i < 18 * 64; i += 256) wg[i] = gcn_w[i];
    __syncthreads();

    const int dg = tid >> 4;          // 16 groups x 4 d
    const int tt = tid & 15;          // 16 groups x 2 t
    const int d0 = dg * 4;
    const int tb = tt * 2;

    float wr[10][4];                  // bone weight rows in registers
    #pragma unroll
    for (int c = 0; c < 10; ++c)
        *(float4*)wr[c] = *(const float4*)(gcn_w + c * 64 + d0);

    const float cP = 1.0f / 6.0f;
    const float cS = 0.23570226039551584f;   // 1/sqrt(18)
    const float c3 = 1.0f / 3.0f;
    const float cT = 0.4082482904638631f;    // 1/sqrt(6)
    const float cH = 0.5f;

    // palm projection h0 (18 channels, weights from LDS)
    float h0[4][2];
    #pragma unroll
    for (int di = 0; di < 4; ++di) h0[di][0] = h0[di][1] = 0.f;
    #pragma unroll 1
    for (int c = 0; c < 18; ++c) {
        float wv[4];
        *(float4*)wv = *(const float4*)(&wg[c * 64 + d0]);
        const float2 xv = *(const float2*)(&xt[c * 36 + tb]);
        #pragma unroll
        for (int di = 0; di < 4; ++di) {
            h0[di][0] = fmaf(wv[di], xv.x, h0[di][0]);
            h0[di][1] = fmaf(wv[di], xv.y, h0[di][1]);
        }
    }

    float pool[4][2], star[4][2];
    #pragma unroll
    for (int di = 0; di < 4; ++di) {
        pool[di][0] = pool[di][1] = 0.f;
        star[di][0] = star[di][1] = 0.f;
    }

    // fingers: nodes sequential, sliding chain state
    #pragma unroll 1
    for (int f = 0; f < 5; ++f) {
        float hn[4][2], hprev[4][2], s12[4][2];
        #pragma unroll
        for (int n = 0; n < 4; ++n) {
            #pragma unroll
            for (int di = 0; di < 4; ++di) hn[di][0] = hn[di][1] = 0.f;
            const int cb = 18 + 10 * (4 * f + n);
            #pragma unroll
            for (int c = 0; c < 10; ++c) {
                const float2 xv = *(const float2*)(&xt[(cb + c) * 36 + tb]);
                #pragma unroll
                for (int di = 0; di < 4; ++di) {
                    hn[di][0] = fmaf(wr[c][di], xv.x, hn[di][0]);
                    hn[di][1] = fmaf(wr[c][di], xv.y, hn[di][1]);
                }
            }
            #pragma unroll
            for (int di = 0; di < 4; ++di)
                #pragma unroll
                for (int ti = 0; ti < 2; ++ti) {
                    const float h = hn[di][ti];
                    if (n == 0) {               // ha
                        star[di][ti] += h;
                        s12[di][ti] = h;
                        hprev[di][ti] = h;
                    } else if (n == 1) {        // h2: pa
                        const float pa = fmaf(cS, h0[di][ti], c3 * (s12[di][ti] + h));
                        pool[di][ti] += fmaxf(pa, 0.f);
                        s12[di][ti] += h;       // ha+h2
                        hprev[di][ti] = h;
                    } else if (n == 2) {        // h3: pb
                        const float pb = c3 * (s12[di][ti] + h);
                        pool[di][ti] += fmaxf(pb, 0.f);
                        s12[di][ti] = hprev[di][ti] + h;  // h2+h3
                        hprev[di][ti] = h;
                    } else {                    // he: pc, pe
                        const float pc = fmaf(cT, h, c3 * s12[di][ti]);
                        const float pe = fmaf(cT, hprev[di][ti], cH * h);
                        pool[di][ti] += fmaxf(pc, 0.f) + fmaxf(pe, 0.f);
                    }
                }
        }
    }

    float* hpb = hp + (long)b * 64 * T_LEN + t0 + tb;
    #pragma unroll
    for (int di = 0; di < 4; ++di) {
        float2 r;
        const float p0a = fmaf(cP, h0[di][0], cS * star[di][0]);
        const float p0b = fmaf(cP, h0[di][1], cS * star[di][1]);
        r.x = (pool[di][0] + fmaxf(p0a, 0.f)) * (1.0f / 21.0f);
        r.y = (pool[di][1] + fmaxf(p0b, 0.f)) * (1.0f / 21.0f);
        *(float2*)(hpb + (long)(d0 + di) * T_LEN) = r;
    }
}

// ---------------------------------------------------------------------------
// k_conv: causal dilated convs + relu -> h.  Class-homogeneous blocks:
//   blockIdx.z == 0: conv_s + conv_m (concat j 0..31), thread = 2j x 8t
//   blockIdx.z == 1: conv_l          (concat j 32..63), thread = 2j x 8t
// t-tile 128; no barrier after staging; waves retire when done.
// ---------------------------------------------------------------------------
__global__ __launch_bounds__(256) void k_conv(
    const float* __restrict__ in,   // [B][64][T]
    const float* __restrict__ ws, const float* __restrict__ bs,
    const float* __restrict__ wm, const float* __restrict__ bm,
    const float* __restrict__ wl, const float* __restrict__ bl,
    float* __restrict__ h)          // [B][64][T]
{
    __shared__ float tile[64 * 164]; // [c][32 halo + 128 t]

    const int b   = blockIdx.y;
    const int t0  = blockIdx.x * 128;
    const int tid = threadIdx.x;
    const int tt  = tid & 15;

    const float* inb = in + (long)b * 64 * T_LEN;
    #pragma unroll 1
    for (int i = tid; i < 64 * 40; i += 256) {
        const int c = i / 40;
        const int q = i - c * 40;
        const int t = t0 - 32 + q * 4;
        float4 v = make_float4(0.f, 0.f, 0.f, 0.f);
        if (t >= 0) v = *(const float4*)(inb + (long)c * T_LEN + t);
        *(float4*)(&tile[c * 164 + q * 4]) = v;
    }
    __syncthreads();

    float acc[2][8];

    if (blockIdx.z == 0) {
        // rotated so alternate blocks swap s-waves and m-waves
        const int jg = ((tid >> 4) + ((blockIdx.x & 1) << 3)) & 15;
        if (jg < 8) {
            // conv_s: k=3, d=1, local n = jg*2 (concat 0..15)
            const int n0 = jg * 2;
            #pragma unroll
            for (int ji = 0; ji < 2; ++ji) {
                const float bv = bs[n0 + ji];
                #pragma unroll
                for (int i = 0; i < 8; ++i) acc[ji][i] = bv;
            }
            const float* wp = ws + n0;         // + (k*64+c)*16
            float w[3][2];
            #pragma unroll
            for (int k = 0; k < 3; ++k) *(float2*)w[k] = *(const float2*)(wp + k * 1024);
            #pragma unroll 1
            for (int c = 0; c < 64; ++c) {
                float win[12];
                const float* rb = &tile[c * 164 + tt * 8 + 28];
                #pragma unroll
                for (int m = 0; m < 3; ++m) *(float4*)(&win[4 * m]) = *(const float4*)(rb + 4 * m);
                const float* wn = wp + (c < 63 ? (c + 1) * 16 : 63 * 16);
                #pragma unroll
                for (int k = 0; k < 3; ++k) {
                    #pragma unroll
                    for (int i = 0; i < 8; ++i) {
                        const float v = win[2 + i + k];
                        acc[0][i] = fmaf(w[k][0], v, acc[0][i]);
                        acc[1][i] = fmaf(w[k][1], v, acc[1][i]);
                    }
                    *(float2*)w[k] = *(const float2*)(wn + k * 1024);
                }
            }
            float* hb = h + (long)b * 64 * T_LEN + t0 + tt * 8;
            #pragma unroll
            for (int ji = 0; ji < 2; ++ji) {
                float* p = hb + (long)(n0 + ji) * T_LEN;
                *(float4*)(p)     = make_float4(fmaxf(acc[ji][0], 0.f), fmaxf(acc[ji][1], 0.f),
                                                fmaxf(acc[ji][2], 0.f), fmaxf(acc[ji][3], 0.f));
                *(float4*)(p + 4) = make_float4(fmaxf(acc[ji][4], 0.f), fmaxf(acc[ji][5], 0.f),
                                                fmaxf(acc[ji][6], 0.f), fmaxf(acc[ji][7], 0.f));
            }
        } else {
            // conv_m: k=5, d=2, local n = (jg-8)*2 (concat 16..31)
            const int n0 = (jg - 8) * 2;
            #pragma unroll
            for (int ji = 0; ji < 2; ++ji) {
                const float bv = bm[n0 + ji];
                #pragma unroll
                for (int i = 0; i < 8; ++i) acc[ji][i] = bv;
            }
            const float* wp = wm + n0;
            float w[5][2];
            #pragma unroll
            for (int k = 0; k < 5; ++k) *(float2*)w[k] = *(const float2*)(wp + k * 1024);
            #pragma unroll 1
            for (int c = 0; c < 64; ++c) {
                float win[16];
                const float* rb = &tile[c * 164 + tt * 8 + 24];
                #pragma unroll
                for (int m = 0; m < 4; ++m) *(float4*)(&win[4 * m]) = *(const float4*)(rb + 4 * m);
                const float* wn = wp + (c < 63 ? (c + 1) * 16 : 63 * 16);
                #pragma unroll
                for (int k = 0; k < 5; ++k) {
                    #pragma unroll
                    for (int i = 0; i < 8; ++i) {
                        const float v = win[i + 2 * k];
                        acc[0][i] = fmaf(w[k][0], v, acc[0][i]);
                        acc[1][i] = fmaf(w[k][1], v, acc[1][i]);
                    }
                    *(float2*)w[k] = *(const float2*)(wn + k * 1024);
                }
            }
            float* hb = h + (long)b * 64 * T_LEN + t0 + tt * 8;
            #pragma unroll
            for (int ji = 0; ji < 2; ++ji) {
                float* p = hb + (long)(16 + n0 + ji) * T_LEN;
                *(float4*)(p)     = make_float4(fmaxf(acc[ji][0], 0.f), fmaxf(acc[ji][1], 0.f),
                                                fmaxf(acc[ji][2], 0.f), fmaxf(acc[ji][3], 0.f));
                *(float4*)(p + 4) = make_float4(fmaxf(acc[ji][4], 0.f), fmaxf(acc[ji][5], 0.f),
                                                fmaxf(acc[ji][6], 0.f), fmaxf(acc[ji][7], 0.f));
            }
        }
    } else {
        // conv_l: k=9, d=4, local n = jg*2 (concat 32..63) — all waves uniform
        const int jg = tid >> 4;
        const int n0 = jg * 2;
        #pragma unroll
        for (int ji = 0; ji < 2; ++ji) {
            const float bv = bl[n0 + ji];
            #pragma unroll
            for (int i = 0; i < 8; ++i) acc[ji][i] = bv;
        }
        const float* wp = wl + n0;             // + (k*64+c)*32
        float w[9][2];
        #pragma unroll
        for (int k = 0; k < 9; ++k) *(float2*)w[k] = *(const float2*)(wp + k * 2048);
        #pragma unroll 1
        for (int c = 0; c < 64; ++c) {
            float win[40];
            const float* rb = &tile[c * 164 + tt * 8];
            #pragma unroll
            for (int m = 0; m < 10; ++m) *(float4*)(&win[4 * m]) = *(const float4*)(rb + 4 * m);
            const float* wn = wp + (c < 63 ? (c + 1) * 32 : 63 * 32);
            #pragma unroll
            for (int k = 0; k < 9; ++k) {
                #pragma unroll
                for (int i = 0; i < 8; ++i) {
                    const float v = win[i + 4 * k];
                    acc[0][i] = fmaf(w[k][0], v, acc[0][i]);
                    acc[1][i] = fmaf(w[k][1], v, acc[1][i]);
                }
                *(float2*)w[k] = *(const float2*)(wn + k * 2048);
            }
        }
        float* hb = h + (long)b * 64 * T_LEN + t0 + tt * 8;
        #pragma unroll
        for (int ji = 0; ji < 2; ++ji) {
            float* p = hb + (long)(32 + n0 + ji) * T_LEN;
            *(float4*)(p)     = make_float4(fmaxf(acc[ji][0], 0.f), fmaxf(acc[ji][1], 0.f),
                                            fmaxf(acc[ji][2], 0.f), fmaxf(acc[ji][3], 0.f));
            *(float4*)(p + 4) = make_float4(fmaxf(acc[ji][4], 0.f), fmaxf(acc[ji][5], 0.f),
                                            fmaxf(acc[ji][6], 0.f), fmaxf(acc[ji][7], 0.f));
        }
    }
}

// ---------------------------------------------------------------------------
// k_convout: 1x1 conv_out 64->64 (no relu), t-tile 128, thread 4d x 8t.
// h-tile and wo both in LDS.  FINAL fuses dense 64->32 + tanh + mean over T.
// ---------------------------------------------------------------------------
template <bool FINAL>
__global__ __launch_bounds__(256) void k_convout(
    const float* __restrict__ h,    // [B][64][T]
    const float* __restrict__ wo,   // [64][64]
    const float* __restrict__ bo,   // [64]
    float* __restrict__ out,        // [B][64][T]  (FINAL=false)
    const float* __restrict__ wd,   // [64][32]    (FINAL=true)
    const float* __restrict__ bd,   // [32]
    float* __restrict__ outp)       // [B][32]     (FINAL=true)
{
    __shared__ float hs[64 * 136];
    __shared__ float wos[64 * 64];

    const int b   = blockIdx.y;
    const int t0  = blockIdx.x * 128;
    const int tid = threadIdx.x;
    const int dg  = tid >> 4;
    const int tt  = tid & 15;
    const int d0  = dg * 4;

    const float* hbase = h + (long)b * 64 * T_LEN + t0;
    #pragma unroll 1
    for (int i = tid; i < 2048; i += 256) {
        const int row = i >> 5;
        const int q   = (i & 31) * 4;
        *(float4*)(&hs[row * 136 + q]) = *(const float4*)(hbase + (long)row * T_LEN + q);
    }
    #pragma unroll 1
    for (int i = tid; i < 1024; i += 256)
        *(float4*)(&wos[i * 4]) = *(const float4*)(wo + i * 4);
    __syncthreads();

    float o[4][8];
    {
        float bv[4];
        *(float4*)bv = *(const float4*)(bo + d0);
        #pragma unroll
        for (int di = 0; di < 4; ++di)
            #pragma unroll
            for (int i = 0; i < 8; ++i) o[di][i] = bv[di];
    }
    #pragma unroll 4
    for (int j = 0; j < 64; ++j) {
        float wv[4], hv[8];
        *(float4*)wv       = *(const float4*)(&wos[j * 64 + d0]);
        *(float4*)(&hv[0]) = *(const float4*)(&hs[j * 136 + tt * 8]);
        *(float4*)(&hv[4]) = *(const float4*)(&hs[j * 136 + tt * 8 + 4]);
        #pragma unroll
        for (int di = 0; di < 4; ++di)
            #pragma unroll
            for (int i = 0; i < 8; ++i)
                o[di][i] = fmaf(wv[di], hv[i], o[di][i]);
    }

    if (!FINAL) {
        float* ob = out + (long)b * 64 * T_LEN + t0 + tt * 8;
        #pragma unroll
        for (int di = 0; di < 4; ++di) {
            float* p = ob + (long)(d0 + di) * T_LEN;
            *(float4*)(p)     = make_float4(o[di][0], o[di][1], o[di][2], o[di][3]);
            *(float4*)(p + 4) = make_float4(o[di][4], o[di][5], o[di][6], o[di][7]);
        }
    } else {
        __syncthreads();
        #pragma unroll
        for (int di = 0; di < 4; ++di) {
            float* p = &hs[(d0 + di) * 136 + tt * 8];
            *(float4*)(p)     = make_float4(o[di][0], o[di][1], o[di][2], o[di][3]);
            *(float4*)(p + 4) = make_float4(o[di][4], o[di][5], o[di][6], o[di][7]);
        }
        __syncthreads();

        const int lane = tid & 63;
        const int wv   = tid >> 6;
        const int e0   = wv * 8;
        float fa[8], fb[8];
        *(float4*)(&fa[0]) = *(const float4*)(bd + e0);
        *(float4*)(&fa[4]) = *(const float4*)(bd + e0 + 4);
        #pragma unroll
        for (int e = 0; e < 8; ++e) fb[e] = fa[e];

        #pragma unroll 4
        for (int d = 0; d < 64; ++d) {
            const float2 hv = *(const float2*)(&hs[d * 136 + lane * 2]);
            float wv8[8];
            *(float4*)(&wv8[0]) = *(const float4*)(wd + d * 32 + e0);
            *(float4*)(&wv8[4]) = *(const float4*)(wd + d * 32 + e0 + 4);
            #pragma unroll
            for (int e = 0; e < 8; ++e) {
                fa[e] = fmaf(wv8[e], hv.x, fa[e]);
                fb[e] = fmaf(wv8[e], hv.y, fb[e]);
            }
        }
        #pragma unroll
        for (int e = 0; e < 8; ++e) {
            float v = (tanhf(fa[e]) + tanhf(fb[e])) * (1.0f / (float)T_LEN);
            v += __shfl_down(v, 32);
            v += __shfl_down(v, 16);
            v += __shfl_down(v, 8);
            v += __shfl_down(v, 4);
            v += __shfl_down(v, 2);
            v += __shfl_down(v, 1);
            if (lane == 0) atomicAdd(&outp[b * 32 + e0 + e], v);
        }
    }
}

extern "C" void kernel_launch(void* const* d_in, const int* in_sizes, int n_in,
                              void* d_out, int out_size, void* d_ws, size_t ws_size,
                              hipStream_t stream) {
    const float* x     = (const float*)d_in[0];
    const float* gcn_w = (const float*)d_in[1];
    const float* wd    = (const float*)d_in[2];
    const float* bd    = (const float*)d_in[3];
    const float* t1_ws = (const float*)d_in[4];
    const float* t1_bs = (const float*)d_in[5];
    const float* t1_wm = (const float*)d_in[6];
    const float* t1_bm = (const float*)d_in[7];
    const float* t1_wl = (const float*)d_in[8];
    const float* t1_bl = (const float*)d_in[9];
    const float* t1_wo = (const float*)d_in[10];
    const float* t1_bo = (const float*)d_in[11];
    const float* t2_ws = (const float*)d_in[12];
    const float* t2_bs = (const float*)d_in[13];
    const float* t2_wm = (const float*)d_in[14];
    const float* t2_bm = (const float*)d_in[15];
    const float* t2_wl = (const float*)d_in[16];
    const float* t2_bl = (const float*)d_in[17];
    const float* t2_wo = (const float*)d_in[18];
    const float* t2_bo = (const float*)d_in[19];

    float* b0 = (float*)d_ws;                          // [16][64][4096]
    float* b1 = b0 + (size_t)BATCH * 64 * T_LEN;       // [16][64][4096]

    hipMemsetAsync(d_out, 0, (size_t)out_size * sizeof(float), stream);

    k_gcn<<<dim3(T_LEN / 32, BATCH), 256, 0, stream>>>(x, gcn_w, b0);

    k_conv<<<dim3(T_LEN / 128, BATCH, 2), 256, 0, stream>>>(
        b0, t1_ws, t1_bs, t1_wm, t1_bm, t1_wl, t1_bl, b1);
    k_convout<false><<<dim3(T_LEN / 128, BATCH), 256, 0, stream>>>(
        b1, t1_wo, t1_bo, b0, nullptr, nullptr, nullptr);

    k_conv<<<dim3(T_LEN / 128, BATCH, 2), 256, 0, stream>>>(
        b0, t2_ws, t2_bs, t2_wm, t2_bm, t2_wl, t2_bl, b1);
    k_convout<true><<<dim3(T_LEN / 128, BATCH), 256, 0, stream>>>(
        b1, t2_wo, t2_bo, nullptr, wd, bd, (float*)d_out);
}

// Round 9
// 355.542 us; speedup vs baseline: 1.0848x; 1.0848x over previous
//
#include <hip/hip_runtime.h>
#include <hip/hip_bf16.h>
#include <math.h>

#define T_LEN 4096
#define BATCH 16

// ---------------------------------------------------------------------------
// k_gcn: adapter + node projections + A_HAT propagation + relu + node-mean.
// (unchanged from R8)
// ---------------------------------------------------------------------------
__global__ __launch_bounds__(256) void k_gcn(
    const float* __restrict__ x,      // [B][T][218]
    const float* __restrict__ gcn_w,  // [18][64]
    float* __restrict__ hp)           // [B][64][T]
{
    __shared__ float xt[218 * 36];
    __shared__ float wg[18 * 64];

    const int b   = blockIdx.y;
    const int t0  = blockIdx.x * 32;
    const int tid = threadIdx.x;

    const float* xb = x + ((long)b * T_LEN + t0) * 218;
    #pragma unroll 1
    for (int i = tid; i < 32 * 218; i += 256) {
        const int t = i / 218;
        const int c = i - 218 * t;
        xt[c * 36 + t] = xb[i];
    }
    for (int i = tid; i < 18 * 64; i += 256) wg[i] = gcn_w[i];
    __syncthreads();

    const int dg = tid >> 4;
    const int tt = tid & 15;
    const int d0 = dg * 4;
    const int tb = tt * 2;

    float wr[10][4];
    #pragma unroll
    for (int c = 0; c < 10; ++c)
        *(float4*)wr[c] = *(const float4*)(gcn_w + c * 64 + d0);

    const float cP = 1.0f / 6.0f;
    const float cS = 0.23570226039551584f;   // 1/sqrt(18)
    const float c3 = 1.0f / 3.0f;
    const float cT = 0.4082482904638631f;    // 1/sqrt(6)
    const float cH = 0.5f;

    float h0[4][2];
    #pragma unroll
    for (int di = 0; di < 4; ++di) h0[di][0] = h0[di][1] = 0.f;
    #pragma unroll 1
    for (int c = 0; c < 18; ++c) {
        float wv[4];
        *(float4*)wv = *(const float4*)(&wg[c * 64 + d0]);
        const float2 xv = *(const float2*)(&xt[c * 36 + tb]);
        #pragma unroll
        for (int di = 0; di < 4; ++di) {
            h0[di][0] = fmaf(wv[di], xv.x, h0[di][0]);
            h0[di][1] = fmaf(wv[di], xv.y, h0[di][1]);
        }
    }

    float pool[4][2], star[4][2];
    #pragma unroll
    for (int di = 0; di < 4; ++di) {
        pool[di][0] = pool[di][1] = 0.f;
        star[di][0] = star[di][1] = 0.f;
    }

    #pragma unroll 1
    for (int f = 0; f < 5; ++f) {
        float hn[4][2], hprev[4][2], s12[4][2];
        #pragma unroll
        for (int n = 0; n < 4; ++n) {
            #pragma unroll
            for (int di = 0; di < 4; ++di) hn[di][0] = hn[di][1] = 0.f;
            const int cb = 18 + 10 * (4 * f + n);
            #pragma unroll
            for (int c = 0; c < 10; ++c) {
                const float2 xv = *(const float2*)(&xt[(cb + c) * 36 + tb]);
                #pragma unroll
                for (int di = 0; di < 4; ++di) {
                    hn[di][0] = fmaf(wr[c][di], xv.x, hn[di][0]);
                    hn[di][1] = fmaf(wr[c][di], xv.y, hn[di][1]);
                }
            }
            #pragma unroll
            for (int di = 0; di < 4; ++di)
                #pragma unroll
                for (int ti = 0; ti < 2; ++ti) {
                    const float h = hn[di][ti];
                    if (n == 0) {
                        star[di][ti] += h;
                        s12[di][ti] = h;
                        hprev[di][ti] = h;
                    } else if (n == 1) {
                        const float pa = fmaf(cS, h0[di][ti], c3 * (s12[di][ti] + h));
                        pool[di][ti] += fmaxf(pa, 0.f);
                        s12[di][ti] += h;
                        hprev[di][ti] = h;
                    } else if (n == 2) {
                        const float pb = c3 * (s12[di][ti] + h);
                        pool[di][ti] += fmaxf(pb, 0.f);
                        s12[di][ti] = hprev[di][ti] + h;
                        hprev[di][ti] = h;
                    } else {
                        const float pc = fmaf(cT, h, c3 * s12[di][ti]);
                        const float pe = fmaf(cT, hprev[di][ti], cH * h);
                        pool[di][ti] += fmaxf(pc, 0.f) + fmaxf(pe, 0.f);
                    }
                }
        }
    }

    float* hpb = hp + (long)b * 64 * T_LEN + t0 + tb;
    #pragma unroll
    for (int di = 0; di < 4; ++di) {
        float2 r;
        const float p0a = fmaf(cP, h0[di][0], cS * star[di][0]);
        const float p0b = fmaf(cP, h0[di][1], cS * star[di][1]);
        r.x = (pool[di][0] + fmaxf(p0a, 0.f)) * (1.0f / 21.0f);
        r.y = (pool[di][1] + fmaxf(p0b, 0.f)) * (1.0f / 21.0f);
        *(float2*)(hpb + (long)(d0 + di) * T_LEN) = r;
    }
}

// ---------------------------------------------------------------------------
// k_mstcn: one full MSTCN, fused, composite-uniform threads.
// block 128 = 8 cjg x 16 tt; t-tile 64 (halo 32); thread owns
//   conv:    2 s-ch + 2 m-ch + 4 l-ch  x 4 t   (J=8, all waves identical)
//   convout: 8 d x 4 t
// One 36-float LDS window per c serves all 17 taps (9 ds_read_b128 per
// 208 FMAs -> 26% LDS duty).  Weights stream from global (VMEM pipe).
// Window reads at stride-4 floats: conflict-free.
// FINAL adds dense 64->32 + tanh + mean over T.
// ---------------------------------------------------------------------------
template <bool FINAL>
__global__ __launch_bounds__(128) void k_mstcn(
    const float* __restrict__ in,   // [B][64][T]
    const float* __restrict__ ws, const float* __restrict__ bs,
    const float* __restrict__ wm, const float* __restrict__ bm,
    const float* __restrict__ wl, const float* __restrict__ bl,
    const float* __restrict__ wo, const float* __restrict__ bo,
    float* __restrict__ out,        // [B][64][T]  (FINAL=false)
    const float* __restrict__ wd,   // [64][32]    (FINAL=true)
    const float* __restrict__ bd,   // [32]
    float* __restrict__ outp)       // [B][32]     (FINAL=true)
{
    __shared__ float smem[64 * 100]; // x-tile [c][96] stride 100; h aliased

    const int b   = blockIdx.y;
    const int t0  = blockIdx.x * 64;
    const int tid = threadIdx.x;
    const int cjg = tid >> 4;        // 0..7 composite j-group
    const int tt  = tid & 15;        // 4 t at tt*4

    // ---- stage x window [t0-32, t0+64) as [c][96], stride 100 ----
    const float* inb = in + (long)b * 64 * T_LEN;
    #pragma unroll 1
    for (int i = tid; i < 64 * 24; i += 128) {
        const int c = i / 24;
        const int q = i - c * 24;
        const int t = t0 - 32 + q * 4;
        float4 v = make_float4(0.f, 0.f, 0.f, 0.f);
        if (t >= 0) v = *(const float4*)(inb + (long)c * T_LEN + t);
        *(float4*)(&smem[c * 100 + q * 4]) = v;
    }
    __syncthreads();

    // ---- conv phase ----
    const int js = 2 * cjg;          // s channels (concat 0..15)
    const int jm = 2 * cjg;          // m channels (concat 16..31)
    const int jl = 4 * cjg;          // l channels (concat 32..63)

    float as[2][4], am[2][4], al[4][4];
    {
        const float2 b2s = *(const float2*)(bs + js);
        const float2 b2m = *(const float2*)(bm + jm);
        float b4l[4];
        *(float4*)b4l = *(const float4*)(bl + jl);
        #pragma unroll
        for (int i = 0; i < 4; ++i) {
            as[0][i] = b2s.x; as[1][i] = b2s.y;
            am[0][i] = b2m.x; am[1][i] = b2m.y;
            #pragma unroll
            for (int j = 0; j < 4; ++j) al[j][i] = b4l[j];
        }
    }

    float2 wsr[3], wmr[5];
    float  wlr[9][4];
    #pragma unroll
    for (int k = 0; k < 3; ++k) wsr[k] = *(const float2*)(ws + (k * 64) * 16 + js);
    #pragma unroll
    for (int k = 0; k < 5; ++k) wmr[k] = *(const float2*)(wm + (k * 64) * 16 + jm);
    #pragma unroll
    for (int k = 0; k < 9; ++k) *(float4*)wlr[k] = *(const float4*)(wl + (k * 64) * 32 + jl);

    #pragma unroll 1
    for (int c = 0; c < 64; ++c) {
        // window: tile cols tt*4 .. tt*4+35  (covers t-32 .. t+3)
        float win[36];
        {
            const float* rb = &smem[c * 100 + tt * 4];
            #pragma unroll
            for (int m = 0; m < 9; ++m)
                *(float4*)(&win[4 * m]) = *(const float4*)(rb + 4 * m);
        }
        const int cn = (c < 63) ? c + 1 : 63;

        // conv_s: x[t-2+k] -> win[30+i+k]
        #pragma unroll
        for (int k = 0; k < 3; ++k) {
            #pragma unroll
            for (int i = 0; i < 4; ++i) {
                const float v = win[30 + i + k];
                as[0][i] = fmaf(wsr[k].x, v, as[0][i]);
                as[1][i] = fmaf(wsr[k].y, v, as[1][i]);
            }
            wsr[k] = *(const float2*)(ws + (k * 64 + cn) * 16 + js);
        }
        // conv_m: x[t-8+2k] -> win[24+i+2k]
        #pragma unroll
        for (int k = 0; k < 5; ++k) {
            #pragma unroll
            for (int i = 0; i < 4; ++i) {
                const float v = win[24 + i + 2 * k];
                am[0][i] = fmaf(wmr[k].x, v, am[0][i]);
                am[1][i] = fmaf(wmr[k].y, v, am[1][i]);
            }
            wmr[k] = *(const float2*)(wm + (k * 64 + cn) * 16 + jm);
        }
        // conv_l: x[t-32+4k] -> win[i+4k]
        #pragma unroll
        for (int k = 0; k < 9; ++k) {
            #pragma unroll
            for (int i = 0; i < 4; ++i) {
                const float v = win[i + 4 * k];
                #pragma unroll
                for (int j = 0; j < 4; ++j)
                    al[j][i] = fmaf(wlr[k][j], v, al[j][i]);
            }
            *(float4*)wlr[k] = *(const float4*)(wl + (k * 64 + cn) * 32 + jl);
        }
    }

    // ---- relu + stage h [64 j][64 t] stride 68 (aliased) ----
    __syncthreads();
    #pragma unroll
    for (int j = 0; j < 2; ++j)
        *(float4*)(&smem[(js + j) * 68 + tt * 4]) =
            make_float4(fmaxf(as[j][0], 0.f), fmaxf(as[j][1], 0.f),
                        fmaxf(as[j][2], 0.f), fmaxf(as[j][3], 0.f));
    #pragma unroll
    for (int j = 0; j < 2; ++j)
        *(float4*)(&smem[(16 + jm + j) * 68 + tt * 4]) =
            make_float4(fmaxf(am[j][0], 0.f), fmaxf(am[j][1], 0.f),
                        fmaxf(am[j][2], 0.f), fmaxf(am[j][3], 0.f));
    #pragma unroll
    for (int j = 0; j < 4; ++j)
        *(float4*)(&smem[(32 + jl + j) * 68 + tt * 4]) =
            make_float4(fmaxf(al[j][0], 0.f), fmaxf(al[j][1], 0.f),
                        fmaxf(al[j][2], 0.f), fmaxf(al[j][3], 0.f));
    __syncthreads();

    // ---- conv_out 64->64 (no relu): thread = 8 d x 4 t ----
    const int d0 = cjg * 8;
    float o[8][4];
    {
        float bv[8];
        *(float4*)(&bv[0]) = *(const float4*)(bo + d0);
        *(float4*)(&bv[4]) = *(const float4*)(bo + d0 + 4);
        #pragma unroll
        for (int di = 0; di < 8; ++di)
            #pragma unroll
            for (int i = 0; i < 4; ++i) o[di][i] = bv[di];
    }
    #pragma unroll 4
    for (int j = 0; j < 64; ++j) {
        float wv[8], hv[4];
        *(float4*)(&wv[0]) = *(const float4*)(wo + j * 64 + d0);
        *(float4*)(&wv[4]) = *(const float4*)(wo + j * 64 + d0 + 4);
        *(float4*)hv       = *(const float4*)(&smem[j * 68 + tt * 4]);
        #pragma unroll
        for (int di = 0; di < 8; ++di)
            #pragma unroll
            for (int i = 0; i < 4; ++i)
                o[di][i] = fmaf(wv[di], hv[i], o[di][i]);
    }

    if (!FINAL) {
        float* ob = out + (long)b * 64 * T_LEN + t0 + tt * 4;
        #pragma unroll
        for (int di = 0; di < 8; ++di)
            *(float4*)(ob + (long)(d0 + di) * T_LEN) =
                make_float4(o[di][0], o[di][1], o[di][2], o[di][3]);
    } else {
        // ---- stage t2 [64 d][64 t], then dense 64->32 + tanh + mean ----
        __syncthreads();
        #pragma unroll
        for (int di = 0; di < 8; ++di)
            *(float4*)(&smem[(d0 + di) * 68 + tt * 4]) =
                make_float4(o[di][0], o[di][1], o[di][2], o[di][3]);
        __syncthreads();

        const int eg = tid >> 5;       // 4 groups x 8 e
        const int e0 = eg * 8;
        const int tl = tid & 31;       // 2 t at tl*2
        float fa[8], fb[8];
        *(float4*)(&fa[0]) = *(const float4*)(bd + e0);
        *(float4*)(&fa[4]) = *(const float4*)(bd + e0 + 4);
        #pragma unroll
        for (int e = 0; e < 8; ++e) fb[e] = fa[e];

        #pragma unroll 4
        for (int d = 0; d < 64; ++d) {
            const float2 hv = *(const float2*)(&smem[d * 68 + tl * 2]);
            float wv[8];
            *(float4*)(&wv[0]) = *(const float4*)(wd + d * 32 + e0);
            *(float4*)(&wv[4]) = *(const float4*)(wd + d * 32 + e0 + 4);
            #pragma unroll
            for (int e = 0; e < 8; ++e) {
                fa[e] = fmaf(wv[e], hv.x, fa[e]);
                fb[e] = fmaf(wv[e], hv.y, fb[e]);
            }
        }
        #pragma unroll
        for (int e = 0; e < 8; ++e) {
            float v = (tanhf(fa[e]) + tanhf(fb[e])) * (1.0f / (float)T_LEN);
            v += __shfl_down(v, 16, 32);
            v += __shfl_down(v, 8, 32);
            v += __shfl_down(v, 4, 32);
            v += __shfl_down(v, 2, 32);
            v += __shfl_down(v, 1, 32);
            if (tl == 0) atomicAdd(&outp[b * 32 + e0 + e], v);
        }
    }
}

extern "C" void kernel_launch(void* const* d_in, const int* in_sizes, int n_in,
                              void* d_out, int out_size, void* d_ws, size_t ws_size,
                              hipStream_t stream) {
    const float* x     = (const float*)d_in[0];
    const float* gcn_w = (const float*)d_in[1];
    const float* wd    = (const float*)d_in[2];
    const float* bd    = (const float*)d_in[3];
    const float* t1_ws = (const float*)d_in[4];
    const float* t1_bs = (const float*)d_in[5];
    const float* t1_wm = (const float*)d_in[6];
    const float* t1_bm = (const float*)d_in[7];
    const float* t1_wl = (const float*)d_in[8];
    const float* t1_bl = (const float*)d_in[9];
    const float* t1_wo = (const float*)d_in[10];
    const float* t1_bo = (const float*)d_in[11];
    const float* t2_ws = (const float*)d_in[12];
    const float* t2_bs = (const float*)d_in[13];
    const float* t2_wm = (const float*)d_in[14];
    const float* t2_bm = (const float*)d_in[15];
    const float* t2_wl = (const float*)d_in[16];
    const float* t2_bl = (const float*)d_in[17];
    const float* t2_wo = (const float*)d_in[18];
    const float* t2_bo = (const float*)d_in[19];

    float* b0 = (float*)d_ws;                          // [16][64][4096]
    float* b1 = b0 + (size_t)BATCH * 64 * T_LEN;       // [16][64][4096]

    hipMemsetAsync(d_out, 0, (size_t)out_size * sizeof(float), stream);

    k_gcn<<<dim3(T_LEN / 32, BATCH), 256, 0, stream>>>(x, gcn_w, b0);

    k_mstcn<false><<<dim3(T_LEN / 64, BATCH), 128, 0, stream>>>(
        b0, t1_ws, t1_bs, t1_wm, t1_bm, t1_wl, t1_bl, t1_wo, t1_bo,
        b1, nullptr, nullptr, nullptr);

    k_mstcn<true><<<dim3(T_LEN / 64, BATCH), 128, 0, stream>>>(
        b1, t2_ws, t2_bs, t2_wm, t2_bm, t2_wl, t2_bl, t2_wo, t2_bo,
        nullptr, wd, bd, (float*)d_out);
}